// Round 10
// baseline (217.411 us; speedup 1.0000x reference)
//
#include <hip/hip_runtime.h>
#include <stdint.h>

#define NBINS 256
#define NCOPY 32  // one sub-histogram per LDS bank; 32 KiB LDS -> 5 blocks/CU
#define HIST_BLOCKS 1280

// Monotonic float<->uint mapping so atomicMin/Max on uint32 order like floats.
__device__ __forceinline__ uint32_t f2mono(float f) {
    uint32_t u = __float_as_uint(f);
    return (u & 0x80000000u) ? ~u : (u | 0x80000000u);
}
__device__ __forceinline__ float mono2f(uint32_t u) {
    uint32_t b = (u & 0x80000000u) ? (u & 0x7FFFFFFFu) : ~u;
    return __uint_as_float(b);
}

// Exact replication of jnp.histogram edge: edges[i] = f32(f32(i*delta) + min)
// Separate roundings, NO fma contraction -> use _rn intrinsics.
__device__ __forceinline__ float edge_at(int i, float minv, float delta) {
    return __fadd_rn(__fmul_rn((float)i, delta), minv);
}

// ws layout (uint32 words):
// [0] min_mono [1] max_mono [2] thresh bits [3] ticket [4..4+NBINS) hist
__global__ void k_init(uint32_t* ws) {
    int i = threadIdx.x;
    if (i == 0) ws[0] = 0xFFFFFFFFu;
    if (i == 1) ws[1] = 0u;
    if (i == 2) ws[2] = 0u;
    if (i == 3) ws[3] = 0u;
    if (i >= 4 && i < 4 + NBINS) ws[i] = 0u;
}

__device__ __forceinline__ float min4(float4 v) {
    return fminf(fminf(v.x, v.y), fminf(v.z, v.w));
}
__device__ __forceinline__ float max4(float4 v) {
    return fmaxf(fmaxf(v.x, v.y), fmaxf(v.z, v.w));
}

__global__ void __launch_bounds__(256) k_minmax(const float* __restrict__ in,
                                                int n, uint32_t* ws) {
    int tid = blockIdx.x * blockDim.x + threadIdx.x;
    int stride = gridDim.x * blockDim.x;
    int n4 = n >> 2;
    const float4* in4 = (const float4*)in;
    float vmin = INFINITY, vmax = -INFINITY;

    // MLP=8: eight independent float4 loads in flight per iteration.
    int i = tid;
    for (; i + 7 * stride < n4; i += 8 * stride) {
        float4 v0 = in4[i];
        float4 v1 = in4[i + stride];
        float4 v2 = in4[i + 2 * stride];
        float4 v3 = in4[i + 3 * stride];
        float4 v4 = in4[i + 4 * stride];
        float4 v5 = in4[i + 5 * stride];
        float4 v6 = in4[i + 6 * stride];
        float4 v7 = in4[i + 7 * stride];
        float mn0 = fminf(fminf(min4(v0), min4(v1)), fminf(min4(v2), min4(v3)));
        float mn1 = fminf(fminf(min4(v4), min4(v5)), fminf(min4(v6), min4(v7)));
        float mx0 = fmaxf(fmaxf(max4(v0), max4(v1)), fmaxf(max4(v2), max4(v3)));
        float mx1 = fmaxf(fmaxf(max4(v4), max4(v5)), fmaxf(max4(v6), max4(v7)));
        vmin = fminf(vmin, fminf(mn0, mn1));
        vmax = fmaxf(vmax, fmaxf(mx0, mx1));
    }
    for (; i < n4; i += stride) {
        float4 v = in4[i];
        vmin = fminf(vmin, min4(v));
        vmax = fmaxf(vmax, max4(v));
    }
    for (int j = (n4 << 2) + tid; j < n; j += stride) {
        float v = in[j];
        vmin = fminf(vmin, v);
        vmax = fmaxf(vmax, v);
    }
#pragma unroll
    for (int off = 32; off > 0; off >>= 1) {
        vmin = fminf(vmin, __shfl_down(vmin, off));
        vmax = fmaxf(vmax, __shfl_down(vmax, off));
    }
    __shared__ float smin[4], smax[4];  // 256 threads = 4 waves
    int wave = threadIdx.x >> 6, lane = threadIdx.x & 63;
    if (lane == 0) { smin[wave] = vmin; smax[wave] = vmax; }
    __syncthreads();
    if (threadIdx.x == 0) {
        float m = smin[0], M = smax[0];
        for (int w = 1; w < 4; ++w) { m = fminf(m, smin[w]); M = fmaxf(M, smax[w]); }
        atomicMin(&ws[0], f2mono(m));
        atomicMax(&ws[1], f2mono(M));
    }
}

// bin = clamp((v-min)*256/(max-min), 0, 255). ±1ulp edge misbinning shifts a
// handful of counts out of 33.5M -> var12 argmax unaffected; threshold value
// itself stays bit-exact (computed from min/max only). v==max subsumed by clamp.
__device__ __forceinline__ int bin_of(float v, float minv, float invd) {
    float t = (v - minv) * invd;
    t = fminf(fmaxf(t, 0.0f), 255.0f);
    return (int)t;
}

// Histogram + (last-finishing block) Otsu threshold -> ws[2].
__global__ void __launch_bounds__(256) k_hist(const float* __restrict__ in,
                                              int n, uint32_t* ws) {
    // h[bin*32 + (lane&31)]: bank = lane&31 -> a wave's ds_add is a free
    // 2-way bank alias; same-address only when lane l and l+32 share a bin.
    __shared__ uint32_t h[NBINS * NCOPY];
    for (int i = threadIdx.x; i < NBINS * NCOPY; i += blockDim.x) h[i] = 0;
    __syncthreads();
    float minv = mono2f(ws[0]);
    float maxv = mono2f(ws[1]);
    float invd = __fdiv_rn(256.0f, __fsub_rn(maxv, minv));
    int c = threadIdx.x & (NCOPY - 1);

    int tid = blockIdx.x * blockDim.x + threadIdx.x;
    int stride = gridDim.x * blockDim.x;
    int n4 = n >> 2;
    const float4* in4 = (const float4*)in;
    int i = tid;
    for (; i + 3 * stride < n4; i += 4 * stride) {
        float4 q0 = in4[i];
        float4 q1 = in4[i + stride];
        float4 q2 = in4[i + 2 * stride];
        float4 q3 = in4[i + 3 * stride];
        atomicAdd(&h[bin_of(q0.x, minv, invd) * NCOPY + c], 1u);
        atomicAdd(&h[bin_of(q0.y, minv, invd) * NCOPY + c], 1u);
        atomicAdd(&h[bin_of(q0.z, minv, invd) * NCOPY + c], 1u);
        atomicAdd(&h[bin_of(q0.w, minv, invd) * NCOPY + c], 1u);
        atomicAdd(&h[bin_of(q1.x, minv, invd) * NCOPY + c], 1u);
        atomicAdd(&h[bin_of(q1.y, minv, invd) * NCOPY + c], 1u);
        atomicAdd(&h[bin_of(q1.z, minv, invd) * NCOPY + c], 1u);
        atomicAdd(&h[bin_of(q1.w, minv, invd) * NCOPY + c], 1u);
        atomicAdd(&h[bin_of(q2.x, minv, invd) * NCOPY + c], 1u);
        atomicAdd(&h[bin_of(q2.y, minv, invd) * NCOPY + c], 1u);
        atomicAdd(&h[bin_of(q2.z, minv, invd) * NCOPY + c], 1u);
        atomicAdd(&h[bin_of(q2.w, minv, invd) * NCOPY + c], 1u);
        atomicAdd(&h[bin_of(q3.x, minv, invd) * NCOPY + c], 1u);
        atomicAdd(&h[bin_of(q3.y, minv, invd) * NCOPY + c], 1u);
        atomicAdd(&h[bin_of(q3.z, minv, invd) * NCOPY + c], 1u);
        atomicAdd(&h[bin_of(q3.w, minv, invd) * NCOPY + c], 1u);
    }
    for (; i < n4; i += stride) {
        float4 q = in4[i];
        atomicAdd(&h[bin_of(q.x, minv, invd) * NCOPY + c], 1u);
        atomicAdd(&h[bin_of(q.y, minv, invd) * NCOPY + c], 1u);
        atomicAdd(&h[bin_of(q.z, minv, invd) * NCOPY + c], 1u);
        atomicAdd(&h[bin_of(q.w, minv, invd) * NCOPY + c], 1u);
    }
    for (int j = (n4 << 2) + tid; j < n; j += stride) {
        atomicAdd(&h[bin_of(in[j], minv, invd) * NCOPY + c], 1u);
    }
    __syncthreads();
    for (int b = threadIdx.x; b < NBINS; b += blockDim.x) {
        uint32_t s = 0;
#pragma unroll
        for (int k = 0; k < NCOPY; ++k) s += h[b * NCOPY + k];
        if (s) atomicAdd(&ws[4 + b], s);
    }

    // ---- last-finishing block computes Otsu -> ws[2] ----
    __shared__ int amLast;
    __threadfence();  // make our hist adds visible before taking a ticket
    if (threadIdx.x == 0) {
        uint32_t t = atomicAdd(&ws[3], 1u);
        amLast = (t == (uint32_t)(gridDim.x - 1)) ? 1 : 0;
    }
    __syncthreads();
    if (!amLast) return;
    __threadfence();  // acquire: see all blocks' hist adds

    {
        float* sf = (float*)h;  // reuse LDS: 7 arrays of 256 floats
        float* cnt = sf;
        float* ctr = sf + NBINS;
        float* w1 = sf + 2 * NBINS;
        float* w2 = sf + 3 * NBINS;
        float* cs = sf + 4 * NBINS;
        float* csr = sf + 5 * NBINS;
        float* scan = sf + 6 * NBINS;
        int i = threadIdx.x;
        float delta = __fdiv_rn(__fsub_rn(maxv, minv), 256.0f);

        __syncthreads();  // everyone done with h before aliasing
        cnt[i] = (float)__hip_atomic_load(&ws[4 + i], __ATOMIC_RELAXED,
                                          __HIP_MEMORY_SCOPE_AGENT);
        float e0 = edge_at(i, minv, delta);
        float e1 = edge_at(i + 1, minv, delta);
        ctr[i] = __fmul_rn(0.5f, __fadd_rn(e0, e1));
        __syncthreads();

        // inclusive prefix scan of cnt -> w1
        scan[i] = cnt[i]; __syncthreads();
        for (int off = 1; off < NBINS; off <<= 1) {
            float v = scan[i];
            if (i >= off) v = __fadd_rn(scan[i - off], v);
            __syncthreads(); scan[i] = v; __syncthreads();
        }
        w1[i] = scan[i]; __syncthreads();

        // inclusive prefix scan of cnt*ctr -> cs
        scan[i] = __fmul_rn(cnt[i], ctr[i]); __syncthreads();
        for (int off = 1; off < NBINS; off <<= 1) {
            float v = scan[i];
            if (i >= off) v = __fadd_rn(scan[i - off], v);
            __syncthreads(); scan[i] = v; __syncthreads();
        }
        cs[i] = scan[i]; __syncthreads();

        // inclusive suffix scan of cnt -> w2
        scan[i] = cnt[i]; __syncthreads();
        for (int off = 1; off < NBINS; off <<= 1) {
            float v = scan[i];
            if (i + off < NBINS) v = __fadd_rn(v, scan[i + off]);
            __syncthreads(); scan[i] = v; __syncthreads();
        }
        w2[i] = scan[i]; __syncthreads();

        // inclusive suffix scan of cnt*ctr -> csr
        scan[i] = __fmul_rn(cnt[i], ctr[i]); __syncthreads();
        for (int off = 1; off < NBINS; off <<= 1) {
            float v = scan[i];
            if (i + off < NBINS) v = __fadd_rn(v, scan[i + off]);
            __syncthreads(); scan[i] = v; __syncthreads();
        }
        csr[i] = scan[i]; __syncthreads();

        // var12[i] = (w1[i]*w2[i+1]) * (m1[i]-m2[i+1])^2, i in [0, 254]
        if (i < NBINS - 1) {
            float m1 = __fdiv_rn(cs[i], fmaxf(w1[i], 1.0f));
            float m2 = __fdiv_rn(csr[i + 1], fmaxf(w2[i + 1], 1.0f));
            float d = __fsub_rn(m1, m2);
            float sq = __fmul_rn(d, d);
            scan[i] = __fmul_rn(__fmul_rn(w1[i], w2[i + 1]), sq);
        }
        __syncthreads();
        if (i == 0) {
            int best = 0; float bv = scan[0];
            for (int k = 1; k < NBINS - 1; ++k) {
                float v = scan[k];
                if (v > bv) { bv = v; best = k; }  // first-max like jnp.argmax
            }
            __hip_atomic_store(&ws[2], __float_as_uint(ctr[best]),
                               __ATOMIC_RELEASE, __HIP_MEMORY_SCOPE_AGENT);
        }
    }
}

// Pure stream: scalar threshold load, then coalesced compare+store.
__global__ void __launch_bounds__(256) k_bin(const float* __restrict__ in,
                                             float* __restrict__ out,
                                             int n, const uint32_t* __restrict__ ws) {
    float t = __uint_as_float(ws[2]);
    int tid = blockIdx.x * blockDim.x + threadIdx.x;
    int stride = gridDim.x * blockDim.x;
    int n4 = n >> 2;
    const float4* in4 = (const float4*)in;
    float4* out4 = (float4*)out;
    int i = tid;
    for (; i + stride < n4; i += 2 * stride) {
        float4 v0 = in4[i];
        float4 v1 = in4[i + stride];
        float4 r0, r1;
        r0.x = v0.x > t ? 1.0f : 0.0f; r0.y = v0.y > t ? 1.0f : 0.0f;
        r0.z = v0.z > t ? 1.0f : 0.0f; r0.w = v0.w > t ? 1.0f : 0.0f;
        r1.x = v1.x > t ? 1.0f : 0.0f; r1.y = v1.y > t ? 1.0f : 0.0f;
        r1.z = v1.z > t ? 1.0f : 0.0f; r1.w = v1.w > t ? 1.0f : 0.0f;
        out4[i] = r0;
        out4[i + stride] = r1;
    }
    for (; i < n4; i += stride) {
        float4 v = in4[i];
        float4 r;
        r.x = v.x > t ? 1.0f : 0.0f;
        r.y = v.y > t ? 1.0f : 0.0f;
        r.z = v.z > t ? 1.0f : 0.0f;
        r.w = v.w > t ? 1.0f : 0.0f;
        out4[i] = r;
    }
    for (int j = (n4 << 2) + tid; j < n; j += stride) {
        out[j] = in[j] > t ? 1.0f : 0.0f;
    }
}

extern "C" void kernel_launch(void* const* d_in, const int* in_sizes, int n_in,
                              void* d_out, int out_size, void* d_ws, size_t ws_size,
                              hipStream_t stream) {
    const float* in = (const float*)d_in[0];
    float* out = (float*)d_out;
    uint32_t* ws = (uint32_t*)d_ws;
    int n = in_sizes[0];

    const int threads = 256;
    const int blocks = 2048;  // 256 CU * 8, grid-stride

    hipLaunchKernelGGL(k_init, dim3(1), dim3(512), 0, stream, ws);
    hipLaunchKernelGGL(k_minmax, dim3(blocks), dim3(threads), 0, stream, in, n, ws);
    hipLaunchKernelGGL(k_hist, dim3(HIST_BLOCKS), dim3(threads), 0, stream, in, n, ws);
    hipLaunchKernelGGL(k_bin, dim3(blocks), dim3(threads), 0, stream, in, out, n, ws);
}

// Round 11
// 183.790 us; speedup vs baseline: 1.1829x; 1.1829x over previous
//
#include <hip/hip_runtime.h>
#include <stdint.h>

#define NBINS 256
#define NCOPY 16  // one sub-histogram per 16 lanes; 16 KiB LDS -> 8 blocks/CU

// Monotonic float<->uint mapping so atomicMin/Max on uint32 order like floats.
__device__ __forceinline__ uint32_t f2mono(float f) {
    uint32_t u = __float_as_uint(f);
    return (u & 0x80000000u) ? ~u : (u | 0x80000000u);
}
__device__ __forceinline__ float mono2f(uint32_t u) {
    uint32_t b = (u & 0x80000000u) ? (u & 0x7FFFFFFFu) : ~u;
    return __uint_as_float(b);
}

// Exact replication of jnp.histogram edge: edges[i] = f32(f32(i*delta) + min)
// Separate roundings, NO fma contraction -> use _rn intrinsics.
__device__ __forceinline__ float edge_at(int i, float minv, float delta) {
    return __fadd_rn(__fmul_rn((float)i, delta), minv);
}

// ws layout (uint32 words):
// [0] min_mono  [1] max_mono  [2] spare  [4..4+NBINS) hist
__global__ void k_init(uint32_t* ws) {
    int i = threadIdx.x;
    if (i == 0) ws[0] = 0xFFFFFFFFu;
    if (i == 1) ws[1] = 0u;
    if (i == 2) ws[2] = 0u;
    if (i >= 4 && i < 4 + NBINS) ws[i] = 0u;
}

__device__ __forceinline__ float min4(float4 v) {
    return fminf(fminf(v.x, v.y), fminf(v.z, v.w));
}
__device__ __forceinline__ float max4(float4 v) {
    return fmaxf(fmaxf(v.x, v.y), fmaxf(v.z, v.w));
}

__global__ void __launch_bounds__(256) k_minmax(const float* __restrict__ in,
                                                int n, uint32_t* ws) {
    int tid = blockIdx.x * blockDim.x + threadIdx.x;
    int stride = gridDim.x * blockDim.x;
    int n4 = n >> 2;
    const float4* in4 = (const float4*)in;
    float vmin = INFINITY, vmax = -INFINITY;

    // MLP=8: eight independent float4 loads in flight per iteration.
    int i = tid;
    for (; i + 7 * stride < n4; i += 8 * stride) {
        float4 v0 = in4[i];
        float4 v1 = in4[i + stride];
        float4 v2 = in4[i + 2 * stride];
        float4 v3 = in4[i + 3 * stride];
        float4 v4 = in4[i + 4 * stride];
        float4 v5 = in4[i + 5 * stride];
        float4 v6 = in4[i + 6 * stride];
        float4 v7 = in4[i + 7 * stride];
        float mn0 = fminf(fminf(min4(v0), min4(v1)), fminf(min4(v2), min4(v3)));
        float mn1 = fminf(fminf(min4(v4), min4(v5)), fminf(min4(v6), min4(v7)));
        float mx0 = fmaxf(fmaxf(max4(v0), max4(v1)), fmaxf(max4(v2), max4(v3)));
        float mx1 = fmaxf(fmaxf(max4(v4), max4(v5)), fmaxf(max4(v6), max4(v7)));
        vmin = fminf(vmin, fminf(mn0, mn1));
        vmax = fmaxf(vmax, fmaxf(mx0, mx1));
    }
    for (; i < n4; i += stride) {
        float4 v = in4[i];
        vmin = fminf(vmin, min4(v));
        vmax = fmaxf(vmax, max4(v));
    }
    for (int j = (n4 << 2) + tid; j < n; j += stride) {
        float v = in[j];
        vmin = fminf(vmin, v);
        vmax = fmaxf(vmax, v);
    }
#pragma unroll
    for (int off = 32; off > 0; off >>= 1) {
        vmin = fminf(vmin, __shfl_down(vmin, off));
        vmax = fmaxf(vmax, __shfl_down(vmax, off));
    }
    __shared__ float smin[4], smax[4];  // 256 threads = 4 waves
    int wave = threadIdx.x >> 6, lane = threadIdx.x & 63;
    if (lane == 0) { smin[wave] = vmin; smax[wave] = vmax; }
    __syncthreads();
    if (threadIdx.x == 0) {
        float m = smin[0], M = smax[0];
        for (int w = 1; w < 4; ++w) { m = fminf(m, smin[w]); M = fmaxf(M, smax[w]); }
        atomicMin(&ws[0], f2mono(m));
        atomicMax(&ws[1], f2mono(M));
    }
}

// bin = clamp((v-min)*256/(max-min), 0, 255). ±1ulp edge misbinning shifts a
// handful of counts out of 33.5M -> var12 argmax unaffected; threshold value
// itself stays bit-exact (computed from min/max only). v==max subsumed by clamp.
__device__ __forceinline__ int bin_of(float v, float minv, float invd) {
    float t = (v - minv) * invd;
    t = fminf(fmaxf(t, 0.0f), 255.0f);
    return (int)t;
}

__device__ __forceinline__ void hist4(float4 q, float minv, float invd,
                                      uint32_t* h, int c) {
    atomicAdd(&h[bin_of(q.x, minv, invd) * NCOPY + c], 1u);
    atomicAdd(&h[bin_of(q.y, minv, invd) * NCOPY + c], 1u);
    atomicAdd(&h[bin_of(q.z, minv, invd) * NCOPY + c], 1u);
    atomicAdd(&h[bin_of(q.w, minv, invd) * NCOPY + c], 1u);
}

// 16 KiB LDS (8 blocks/CU => 32 waves/CU), MLP=8: latency-bound fix is
// waves x bytes-in-flight, not bigger sub-histogram count (R10 post-mortem).
__global__ void __launch_bounds__(256, 8) k_hist(const float* __restrict__ in,
                                                 int n, uint32_t* ws) {
    __shared__ uint32_t h[NBINS * NCOPY];
    for (int i = threadIdx.x; i < NBINS * NCOPY; i += blockDim.x) h[i] = 0;
    __syncthreads();
    float minv = mono2f(ws[0]);
    float maxv = mono2f(ws[1]);
    float invd = __fdiv_rn(256.0f, __fsub_rn(maxv, minv));
    int c = threadIdx.x & (NCOPY - 1);

    int tid = blockIdx.x * blockDim.x + threadIdx.x;
    int stride = gridDim.x * blockDim.x;
    int n4 = n >> 2;
    const float4* in4 = (const float4*)in;
    int i = tid;
    for (; i + 7 * stride < n4; i += 8 * stride) {
        float4 q0 = in4[i];
        float4 q1 = in4[i + stride];
        float4 q2 = in4[i + 2 * stride];
        float4 q3 = in4[i + 3 * stride];
        float4 q4 = in4[i + 4 * stride];
        float4 q5 = in4[i + 5 * stride];
        float4 q6 = in4[i + 6 * stride];
        float4 q7 = in4[i + 7 * stride];
        hist4(q0, minv, invd, h, c);
        hist4(q1, minv, invd, h, c);
        hist4(q2, minv, invd, h, c);
        hist4(q3, minv, invd, h, c);
        hist4(q4, minv, invd, h, c);
        hist4(q5, minv, invd, h, c);
        hist4(q6, minv, invd, h, c);
        hist4(q7, minv, invd, h, c);
    }
    for (; i < n4; i += stride) {
        float4 q = in4[i];
        hist4(q, minv, invd, h, c);
    }
    for (int j = (n4 << 2) + tid; j < n; j += stride) {
        atomicAdd(&h[bin_of(in[j], minv, invd) * NCOPY + c], 1u);
    }
    __syncthreads();
    for (int b = threadIdx.x; b < NBINS; b += blockDim.x) {
        uint32_t s = 0;
#pragma unroll
        for (int k = 0; k < NCOPY; ++k) s += h[b * NCOPY + k];
        if (s) atomicAdd(&ws[4 + b], s);
    }
}

// Binarize with Otsu folded in: EVERY block redundantly computes the threshold
// from the global histogram (identical f32 math -> identical bit-exact result),
// then streams its slice.
__global__ void __launch_bounds__(256) k_bin(const float* __restrict__ in,
                                             float* __restrict__ out,
                                             int n, const uint32_t* __restrict__ ws) {
    __shared__ float cnt[NBINS], ctr[NBINS], w1[NBINS], w2[NBINS],
                     cs[NBINS], csr[NBINS], scan[NBINS], tsh[1];
    {
        int i = threadIdx.x;
        float minv = mono2f(ws[0]);
        float maxv = mono2f(ws[1]);
        float delta = __fdiv_rn(__fsub_rn(maxv, minv), 256.0f);

        cnt[i] = (float)ws[4 + i];
        float e0 = edge_at(i, minv, delta);
        float e1 = edge_at(i + 1, minv, delta);
        ctr[i] = __fmul_rn(0.5f, __fadd_rn(e0, e1));
        __syncthreads();

        // inclusive prefix scan of cnt -> w1
        scan[i] = cnt[i]; __syncthreads();
        for (int off = 1; off < NBINS; off <<= 1) {
            float v = scan[i];
            if (i >= off) v = __fadd_rn(scan[i - off], v);
            __syncthreads(); scan[i] = v; __syncthreads();
        }
        w1[i] = scan[i]; __syncthreads();

        // inclusive prefix scan of cnt*ctr -> cs
        scan[i] = __fmul_rn(cnt[i], ctr[i]); __syncthreads();
        for (int off = 1; off < NBINS; off <<= 1) {
            float v = scan[i];
            if (i >= off) v = __fadd_rn(scan[i - off], v);
            __syncthreads(); scan[i] = v; __syncthreads();
        }
        cs[i] = scan[i]; __syncthreads();

        // inclusive suffix scan of cnt -> w2
        scan[i] = cnt[i]; __syncthreads();
        for (int off = 1; off < NBINS; off <<= 1) {
            float v = scan[i];
            if (i + off < NBINS) v = __fadd_rn(v, scan[i + off]);
            __syncthreads(); scan[i] = v; __syncthreads();
        }
        w2[i] = scan[i]; __syncthreads();

        // inclusive suffix scan of cnt*ctr -> csr
        scan[i] = __fmul_rn(cnt[i], ctr[i]); __syncthreads();
        for (int off = 1; off < NBINS; off <<= 1) {
            float v = scan[i];
            if (i + off < NBINS) v = __fadd_rn(v, scan[i + off]);
            __syncthreads(); scan[i] = v; __syncthreads();
        }
        csr[i] = scan[i]; __syncthreads();

        // var12[i] = (w1[i]*w2[i+1]) * (m1[i]-m2[i+1])^2, i in [0, 254]
        if (i < NBINS - 1) {
            float m1 = __fdiv_rn(cs[i], fmaxf(w1[i], 1.0f));
            float m2 = __fdiv_rn(csr[i + 1], fmaxf(w2[i + 1], 1.0f));
            float d = __fsub_rn(m1, m2);
            float sq = __fmul_rn(d, d);
            scan[i] = __fmul_rn(__fmul_rn(w1[i], w2[i + 1]), sq);
        }
        __syncthreads();
        if (i == 0) {
            int best = 0; float bv = scan[0];
            for (int k = 1; k < NBINS - 1; ++k) {
                float v = scan[k];
                if (v > bv) { bv = v; best = k; }  // first-max like jnp.argmax
            }
            tsh[0] = ctr[best];
        }
        __syncthreads();
    }
    float t = tsh[0];

    int tid = blockIdx.x * blockDim.x + threadIdx.x;
    int stride = gridDim.x * blockDim.x;
    int n4 = n >> 2;
    const float4* in4 = (const float4*)in;
    float4* out4 = (float4*)out;
    int i = tid;
    for (; i + 3 * stride < n4; i += 4 * stride) {
        float4 v0 = in4[i];
        float4 v1 = in4[i + stride];
        float4 v2 = in4[i + 2 * stride];
        float4 v3 = in4[i + 3 * stride];
        float4 r0, r1, r2, r3;
        r0.x = v0.x > t ? 1.0f : 0.0f; r0.y = v0.y > t ? 1.0f : 0.0f;
        r0.z = v0.z > t ? 1.0f : 0.0f; r0.w = v0.w > t ? 1.0f : 0.0f;
        r1.x = v1.x > t ? 1.0f : 0.0f; r1.y = v1.y > t ? 1.0f : 0.0f;
        r1.z = v1.z > t ? 1.0f : 0.0f; r1.w = v1.w > t ? 1.0f : 0.0f;
        r2.x = v2.x > t ? 1.0f : 0.0f; r2.y = v2.y > t ? 1.0f : 0.0f;
        r2.z = v2.z > t ? 1.0f : 0.0f; r2.w = v2.w > t ? 1.0f : 0.0f;
        r3.x = v3.x > t ? 1.0f : 0.0f; r3.y = v3.y > t ? 1.0f : 0.0f;
        r3.z = v3.z > t ? 1.0f : 0.0f; r3.w = v3.w > t ? 1.0f : 0.0f;
        out4[i] = r0;
        out4[i + stride] = r1;
        out4[i + 2 * stride] = r2;
        out4[i + 3 * stride] = r3;
    }
    for (; i < n4; i += stride) {
        float4 v = in4[i];
        float4 r;
        r.x = v.x > t ? 1.0f : 0.0f;
        r.y = v.y > t ? 1.0f : 0.0f;
        r.z = v.z > t ? 1.0f : 0.0f;
        r.w = v.w > t ? 1.0f : 0.0f;
        out4[i] = r;
    }
    for (int j = (n4 << 2) + tid; j < n; j += stride) {
        out[j] = in[j] > t ? 1.0f : 0.0f;
    }
}

extern "C" void kernel_launch(void* const* d_in, const int* in_sizes, int n_in,
                              void* d_out, int out_size, void* d_ws, size_t ws_size,
                              hipStream_t stream) {
    const float* in = (const float*)d_in[0];
    float* out = (float*)d_out;
    uint32_t* ws = (uint32_t*)d_ws;
    int n = in_sizes[0];

    const int threads = 256;
    const int blocks = 2048;  // 256 CU * 8, grid-stride

    hipLaunchKernelGGL(k_init, dim3(1), dim3(512), 0, stream, ws);
    hipLaunchKernelGGL(k_minmax, dim3(blocks), dim3(threads), 0, stream, in, n, ws);
    hipLaunchKernelGGL(k_hist, dim3(blocks), dim3(threads), 0, stream, in, n, ws);
    hipLaunchKernelGGL(k_bin, dim3(blocks), dim3(threads), 0, stream, in, out, n, ws);
}

// Round 12
// 173.930 us; speedup vs baseline: 1.2500x; 1.0567x over previous
//
#include <hip/hip_runtime.h>
#include <stdint.h>

#define NBINS 256
#define NCOPY 32  // one sub-histogram per LDS bank; 32 KiB LDS -> 5 blocks/CU

typedef float f32x4 __attribute__((ext_vector_type(4)));  // nt-load/store compatible

// Monotonic float<->uint mapping so atomicMin/Max on uint32 order like floats.
__device__ __forceinline__ uint32_t f2mono(float f) {
    uint32_t u = __float_as_uint(f);
    return (u & 0x80000000u) ? ~u : (u | 0x80000000u);
}
__device__ __forceinline__ float mono2f(uint32_t u) {
    uint32_t b = (u & 0x80000000u) ? (u & 0x7FFFFFFFu) : ~u;
    return __uint_as_float(b);
}

// Exact replication of jnp.histogram edge: edges[i] = f32(f32(i*delta) + min)
// Separate roundings, NO fma contraction -> use _rn intrinsics.
__device__ __forceinline__ float edge_at(int i, float minv, float delta) {
    return __fadd_rn(__fmul_rn((float)i, delta), minv);
}

// ws layout (uint32 words):
// [0] min_mono  [1] max_mono  [2] spare  [4..4+NBINS) hist
__global__ void k_init(uint32_t* ws) {
    int i = threadIdx.x;
    if (i == 0) ws[0] = 0xFFFFFFFFu;
    if (i == 1) ws[1] = 0u;
    if (i == 2) ws[2] = 0u;
    if (i >= 4 && i < 4 + NBINS) ws[i] = 0u;
}

__device__ __forceinline__ float min4(f32x4 v) {
    return fminf(fminf(v.x, v.y), fminf(v.z, v.w));
}
__device__ __forceinline__ float max4(f32x4 v) {
    return fmaxf(fmaxf(v.x, v.y), fmaxf(v.z, v.w));
}
// Streaming read-once: bypass L1 allocation (nt) — reads are the slow path,
// the harness fill proves plain WRITES already stream at 7 TB/s.
__device__ __forceinline__ f32x4 ntload(const f32x4* p) {
    return __builtin_nontemporal_load(p);
}

__global__ void __launch_bounds__(256) k_minmax(const float* __restrict__ in,
                                                int n, uint32_t* ws) {
    int tid = blockIdx.x * blockDim.x + threadIdx.x;
    int stride = gridDim.x * blockDim.x;
    int n4 = n >> 2;
    const f32x4* in4 = (const f32x4*)in;
    float vmin = INFINITY, vmax = -INFINITY;

    // MLP=8: eight independent nt float4 loads in flight per iteration.
    int i = tid;
    for (; i + 7 * stride < n4; i += 8 * stride) {
        f32x4 v0 = ntload(&in4[i]);
        f32x4 v1 = ntload(&in4[i + stride]);
        f32x4 v2 = ntload(&in4[i + 2 * stride]);
        f32x4 v3 = ntload(&in4[i + 3 * stride]);
        f32x4 v4 = ntload(&in4[i + 4 * stride]);
        f32x4 v5 = ntload(&in4[i + 5 * stride]);
        f32x4 v6 = ntload(&in4[i + 6 * stride]);
        f32x4 v7 = ntload(&in4[i + 7 * stride]);
        float mn0 = fminf(fminf(min4(v0), min4(v1)), fminf(min4(v2), min4(v3)));
        float mn1 = fminf(fminf(min4(v4), min4(v5)), fminf(min4(v6), min4(v7)));
        float mx0 = fmaxf(fmaxf(max4(v0), max4(v1)), fmaxf(max4(v2), max4(v3)));
        float mx1 = fmaxf(fmaxf(max4(v4), max4(v5)), fmaxf(max4(v6), max4(v7)));
        vmin = fminf(vmin, fminf(mn0, mn1));
        vmax = fmaxf(vmax, fmaxf(mx0, mx1));
    }
    for (; i < n4; i += stride) {
        f32x4 v = ntload(&in4[i]);
        vmin = fminf(vmin, min4(v));
        vmax = fmaxf(vmax, max4(v));
    }
    for (int j = (n4 << 2) + tid; j < n; j += stride) {
        float v = in[j];
        vmin = fminf(vmin, v);
        vmax = fmaxf(vmax, v);
    }
#pragma unroll
    for (int off = 32; off > 0; off >>= 1) {
        vmin = fminf(vmin, __shfl_down(vmin, off));
        vmax = fmaxf(vmax, __shfl_down(vmax, off));
    }
    __shared__ float smin[4], smax[4];  // 256 threads = 4 waves
    int wave = threadIdx.x >> 6, lane = threadIdx.x & 63;
    if (lane == 0) { smin[wave] = vmin; smax[wave] = vmax; }
    __syncthreads();
    if (threadIdx.x == 0) {
        float m = smin[0], M = smax[0];
        for (int w = 1; w < 4; ++w) { m = fminf(m, smin[w]); M = fmaxf(M, smax[w]); }
        atomicMin(&ws[0], f2mono(m));
        atomicMax(&ws[1], f2mono(M));
    }
}

// bin = clamp((v-min)*256/(max-min), 0, 255). ±1ulp edge misbinning shifts a
// handful of counts out of 33.5M -> var12 argmax unaffected; threshold value
// itself stays bit-exact (computed from min/max only). v==max subsumed by clamp.
__device__ __forceinline__ int bin_of(float v, float minv, float invd) {
    float t = (v - minv) * invd;
    t = fminf(fmaxf(t, 0.0f), 255.0f);
    return (int)t;
}

__device__ __forceinline__ void hist4(f32x4 q, float minv, float invd,
                                      uint32_t* h, int c) {
    atomicAdd(&h[bin_of(q.x, minv, invd) * NCOPY + c], 1u);
    atomicAdd(&h[bin_of(q.y, minv, invd) * NCOPY + c], 1u);
    atomicAdd(&h[bin_of(q.z, minv, invd) * NCOPY + c], 1u);
    atomicAdd(&h[bin_of(q.w, minv, invd) * NCOPY + c], 1u);
}

__global__ void __launch_bounds__(256) k_hist(const float* __restrict__ in,
                                              int n, uint32_t* ws) {
    // h[bin*32 + (lane&31)]: bank = lane&31 -> a wave's ds_add is a free
    // 2-way bank alias; same-address only when lane l and l+32 share a bin.
    __shared__ uint32_t h[NBINS * NCOPY];
    for (int i = threadIdx.x; i < NBINS * NCOPY; i += blockDim.x) h[i] = 0;
    __syncthreads();
    float minv = mono2f(ws[0]);
    float maxv = mono2f(ws[1]);
    float invd = __fdiv_rn(256.0f, __fsub_rn(maxv, minv));
    int c = threadIdx.x & (NCOPY - 1);

    int tid = blockIdx.x * blockDim.x + threadIdx.x;
    int stride = gridDim.x * blockDim.x;
    int n4 = n >> 2;
    const f32x4* in4 = (const f32x4*)in;
    int i = tid;
    for (; i + 3 * stride < n4; i += 4 * stride) {
        f32x4 q0 = ntload(&in4[i]);
        f32x4 q1 = ntload(&in4[i + stride]);
        f32x4 q2 = ntload(&in4[i + 2 * stride]);
        f32x4 q3 = ntload(&in4[i + 3 * stride]);
        hist4(q0, minv, invd, h, c);
        hist4(q1, minv, invd, h, c);
        hist4(q2, minv, invd, h, c);
        hist4(q3, minv, invd, h, c);
    }
    for (; i < n4; i += stride) {
        f32x4 q = ntload(&in4[i]);
        hist4(q, minv, invd, h, c);
    }
    for (int j = (n4 << 2) + tid; j < n; j += stride) {
        atomicAdd(&h[bin_of(in[j], minv, invd) * NCOPY + c], 1u);
    }
    __syncthreads();
    for (int b = threadIdx.x; b < NBINS; b += blockDim.x) {
        uint32_t s = 0;
#pragma unroll
        for (int k = 0; k < NCOPY; ++k) s += h[b * NCOPY + k];
        if (s) atomicAdd(&ws[4 + b], s);
    }
}

// Binarize with Otsu folded in: EVERY block redundantly computes the threshold
// from the global histogram (identical f32 math -> identical bit-exact result),
// then streams its slice.
__global__ void __launch_bounds__(256) k_bin(const float* __restrict__ in,
                                             float* __restrict__ out,
                                             int n, const uint32_t* __restrict__ ws) {
    __shared__ float cnt[NBINS], ctr[NBINS], w1[NBINS], w2[NBINS],
                     cs[NBINS], csr[NBINS], scan[NBINS], tsh[1];
    {
        int i = threadIdx.x;
        float minv = mono2f(ws[0]);
        float maxv = mono2f(ws[1]);
        float delta = __fdiv_rn(__fsub_rn(maxv, minv), 256.0f);

        cnt[i] = (float)ws[4 + i];
        float e0 = edge_at(i, minv, delta);
        float e1 = edge_at(i + 1, minv, delta);
        ctr[i] = __fmul_rn(0.5f, __fadd_rn(e0, e1));
        __syncthreads();

        // inclusive prefix scan of cnt -> w1
        scan[i] = cnt[i]; __syncthreads();
        for (int off = 1; off < NBINS; off <<= 1) {
            float v = scan[i];
            if (i >= off) v = __fadd_rn(scan[i - off], v);
            __syncthreads(); scan[i] = v; __syncthreads();
        }
        w1[i] = scan[i]; __syncthreads();

        // inclusive prefix scan of cnt*ctr -> cs
        scan[i] = __fmul_rn(cnt[i], ctr[i]); __syncthreads();
        for (int off = 1; off < NBINS; off <<= 1) {
            float v = scan[i];
            if (i >= off) v = __fadd_rn(scan[i - off], v);
            __syncthreads(); scan[i] = v; __syncthreads();
        }
        cs[i] = scan[i]; __syncthreads();

        // inclusive suffix scan of cnt -> w2
        scan[i] = cnt[i]; __syncthreads();
        for (int off = 1; off < NBINS; off <<= 1) {
            float v = scan[i];
            if (i + off < NBINS) v = __fadd_rn(v, scan[i + off]);
            __syncthreads(); scan[i] = v; __syncthreads();
        }
        w2[i] = scan[i]; __syncthreads();

        // inclusive suffix scan of cnt*ctr -> csr
        scan[i] = __fmul_rn(cnt[i], ctr[i]); __syncthreads();
        for (int off = 1; off < NBINS; off <<= 1) {
            float v = scan[i];
            if (i + off < NBINS) v = __fadd_rn(v, scan[i + off]);
            __syncthreads(); scan[i] = v; __syncthreads();
        }
        csr[i] = scan[i]; __syncthreads();

        // var12[i] = (w1[i]*w2[i+1]) * (m1[i]-m2[i+1])^2, i in [0, 254]
        if (i < NBINS - 1) {
            float m1 = __fdiv_rn(cs[i], fmaxf(w1[i], 1.0f));
            float m2 = __fdiv_rn(csr[i + 1], fmaxf(w2[i + 1], 1.0f));
            float d = __fsub_rn(m1, m2);
            float sq = __fmul_rn(d, d);
            scan[i] = __fmul_rn(__fmul_rn(w1[i], w2[i + 1]), sq);
        }
        __syncthreads();
        if (i == 0) {
            int best = 0; float bv = scan[0];
            for (int k = 1; k < NBINS - 1; ++k) {
                float v = scan[k];
                if (v > bv) { bv = v; best = k; }  // first-max like jnp.argmax
            }
            tsh[0] = ctr[best];
        }
        __syncthreads();
    }
    float t = tsh[0];

    int tid = blockIdx.x * blockDim.x + threadIdx.x;
    int stride = gridDim.x * blockDim.x;
    int n4 = n >> 2;
    const f32x4* in4 = (const f32x4*)in;
    f32x4* out4 = (f32x4*)out;
    int i = tid;
    for (; i + 3 * stride < n4; i += 4 * stride) {
        f32x4 v0 = ntload(&in4[i]);
        f32x4 v1 = ntload(&in4[i + stride]);
        f32x4 v2 = ntload(&in4[i + 2 * stride]);
        f32x4 v3 = ntload(&in4[i + 3 * stride]);
        f32x4 r0, r1, r2, r3;
        r0.x = v0.x > t ? 1.0f : 0.0f; r0.y = v0.y > t ? 1.0f : 0.0f;
        r0.z = v0.z > t ? 1.0f : 0.0f; r0.w = v0.w > t ? 1.0f : 0.0f;
        r1.x = v1.x > t ? 1.0f : 0.0f; r1.y = v1.y > t ? 1.0f : 0.0f;
        r1.z = v1.z > t ? 1.0f : 0.0f; r1.w = v1.w > t ? 1.0f : 0.0f;
        r2.x = v2.x > t ? 1.0f : 0.0f; r2.y = v2.y > t ? 1.0f : 0.0f;
        r2.z = v2.z > t ? 1.0f : 0.0f; r2.w = v2.w > t ? 1.0f : 0.0f;
        r3.x = v3.x > t ? 1.0f : 0.0f; r3.y = v3.y > t ? 1.0f : 0.0f;
        r3.z = v3.z > t ? 1.0f : 0.0f; r3.w = v3.w > t ? 1.0f : 0.0f;
        out4[i] = r0;
        out4[i + stride] = r1;
        out4[i + 2 * stride] = r2;
        out4[i + 3 * stride] = r3;
    }
    for (; i < n4; i += stride) {
        f32x4 v = ntload(&in4[i]);
        f32x4 r;
        r.x = v.x > t ? 1.0f : 0.0f;
        r.y = v.y > t ? 1.0f : 0.0f;
        r.z = v.z > t ? 1.0f : 0.0f;
        r.w = v.w > t ? 1.0f : 0.0f;
        out4[i] = r;
    }
    for (int j = (n4 << 2) + tid; j < n; j += stride) {
        out[j] = in[j] > t ? 1.0f : 0.0f;
    }
}

extern "C" void kernel_launch(void* const* d_in, const int* in_sizes, int n_in,
                              void* d_out, int out_size, void* d_ws, size_t ws_size,
                              hipStream_t stream) {
    const float* in = (const float*)d_in[0];
    float* out = (float*)d_out;
    uint32_t* ws = (uint32_t*)d_ws;
    int n = in_sizes[0];

    const int threads = 256;
    const int blocks = 2048;       // 256 CU * 8, grid-stride
    const int hist_blocks = 1280;  // 5 blocks/CU resident (32 KiB LDS each)

    hipLaunchKernelGGL(k_init, dim3(1), dim3(512), 0, stream, ws);
    hipLaunchKernelGGL(k_minmax, dim3(blocks), dim3(threads), 0, stream, in, n, ws);
    hipLaunchKernelGGL(k_hist, dim3(hist_blocks), dim3(threads), 0, stream, in, n, ws);
    hipLaunchKernelGGL(k_bin, dim3(blocks), dim3(threads), 0, stream, in, out, n, ws);
}

// Round 13
// 149.660 us; speedup vs baseline: 1.4527x; 1.1622x over previous
//
#include <hip/hip_runtime.h>
#include <stdint.h>

#define NBINS 256
#define NCOPY 32      // one sub-histogram per LDS bank; 32 KiB LDS
#define GRID 2048     // grid for all streaming kernels
#define TPB 256
// ws word layout:
#define HOFF 4              // hist bins [4..260), zeroed by k_minmax block 0
#define MOFF 512            // per-block mins  [512..512+GRID)
#define XOFF (512 + GRID)   // per-block maxs  [..+GRID)

// Exact replication of jnp.histogram edge: edges[i] = f32(f32(i*delta) + min)
// Separate roundings, NO fma contraction -> use _rn intrinsics.
__device__ __forceinline__ float edge_at(int i, float minv, float delta) {
    return __fadd_rn(__fmul_rn((float)i, delta), minv);
}

__device__ __forceinline__ float min4(float4 v) {
    return fminf(fminf(v.x, v.y), fminf(v.z, v.w));
}
__device__ __forceinline__ float max4(float4 v) {
    return fmaxf(fmaxf(v.x, v.y), fmaxf(v.z, v.w));
}

// Contiguous-chunk-per-block: block b owns float4 range [b*chunk,(b+1)*chunk).
// Waves stream sequential 1KB lines through a contiguous region (DRAM-page
// friendly) instead of 8.4MB-strided jumps (the R12 theory for the ~2.5TB/s cap).

__global__ void __launch_bounds__(TPB) k_minmax(const float* __restrict__ in,
                                                int n, uint32_t* ws) {
    float* fws = (float*)ws;
    int n4 = n >> 2;
    int chunk = (n4 + GRID - 1) / GRID;
    int start = blockIdx.x * chunk;
    int end = start + chunk; if (end > n4) end = n4;
    const float4* in4 = (const float4*)in;
    float vmin = INFINITY, vmax = -INFINITY;

    int i = start + threadIdx.x;
    for (; i + 7 * TPB < end; i += 8 * TPB) {  // MLP=8, sequential lines
        float4 v0 = in4[i];
        float4 v1 = in4[i + TPB];
        float4 v2 = in4[i + 2 * TPB];
        float4 v3 = in4[i + 3 * TPB];
        float4 v4 = in4[i + 4 * TPB];
        float4 v5 = in4[i + 5 * TPB];
        float4 v6 = in4[i + 6 * TPB];
        float4 v7 = in4[i + 7 * TPB];
        float mn0 = fminf(fminf(min4(v0), min4(v1)), fminf(min4(v2), min4(v3)));
        float mn1 = fminf(fminf(min4(v4), min4(v5)), fminf(min4(v6), min4(v7)));
        float mx0 = fmaxf(fmaxf(max4(v0), max4(v1)), fmaxf(max4(v2), max4(v3)));
        float mx1 = fmaxf(fmaxf(max4(v4), max4(v5)), fmaxf(max4(v6), max4(v7)));
        vmin = fminf(vmin, fminf(mn0, mn1));
        vmax = fmaxf(vmax, fmaxf(mx0, mx1));
    }
    for (; i < end; i += TPB) {
        float4 v = in4[i];
        vmin = fminf(vmin, min4(v));
        vmax = fmaxf(vmax, max4(v));
    }
    for (int j = (n4 << 2) + blockIdx.x * TPB + threadIdx.x; j < n; j += GRID * TPB) {
        float v = in[j];
        vmin = fminf(vmin, v);
        vmax = fmaxf(vmax, v);
    }
#pragma unroll
    for (int off = 32; off > 0; off >>= 1) {
        vmin = fminf(vmin, __shfl_down(vmin, off));
        vmax = fmaxf(vmax, __shfl_down(vmax, off));
    }
    __shared__ float smin[4], smax[4];
    int wave = threadIdx.x >> 6, lane = threadIdx.x & 63;
    if (lane == 0) { smin[wave] = vmin; smax[wave] = vmax; }
    __syncthreads();
    if (threadIdx.x == 0) {
        float m = fminf(fminf(smin[0], smin[1]), fminf(smin[2], smin[3]));
        float M = fmaxf(fmaxf(smax[0], smax[1]), fmaxf(smax[2], smax[3]));
        fws[MOFF + blockIdx.x] = m;   // plain per-block slots: no init needed
        fws[XOFF + blockIdx.x] = M;
    }
    if (blockIdx.x == 0) ws[HOFF + threadIdx.x] = 0;  // zero bins for k_hist
}

// bin = clamp((v-min)*256/(max-min), 0, 255). ±1ulp edge misbinning shifts a
// handful of counts out of 33.5M -> var12 argmax unaffected; threshold value
// itself stays bit-exact (computed from min/max only). v==max subsumed by clamp.
__device__ __forceinline__ int bin_of(float v, float minv, float invd) {
    float t = (v - minv) * invd;
    t = fminf(fmaxf(t, 0.0f), 255.0f);
    return (int)t;
}

__device__ __forceinline__ void hist4(float4 q, float minv, float invd,
                                      uint32_t* h, int c) {
    atomicAdd(&h[bin_of(q.x, minv, invd) * NCOPY + c], 1u);
    atomicAdd(&h[bin_of(q.y, minv, invd) * NCOPY + c], 1u);
    atomicAdd(&h[bin_of(q.z, minv, invd) * NCOPY + c], 1u);
    atomicAdd(&h[bin_of(q.w, minv, invd) * NCOPY + c], 1u);
}

__global__ void __launch_bounds__(TPB) k_hist(const float* __restrict__ in,
                                              int n, uint32_t* ws) {
    __shared__ uint32_t h[NBINS * NCOPY];  // 32 KiB exactly (no extra LDS!)
    float* hf = (float*)h;
    float* fws = (float*)ws;

    // prologue: reduce per-block min/max slots (uses h as scratch pre-zero)
    float lmin = INFINITY, lmax = -INFINITY;
    for (int k = threadIdx.x; k < GRID; k += TPB) {
        lmin = fminf(lmin, fws[MOFF + k]);
        lmax = fmaxf(lmax, fws[XOFF + k]);
    }
#pragma unroll
    for (int off = 32; off > 0; off >>= 1) {
        lmin = fminf(lmin, __shfl_down(lmin, off));
        lmax = fmaxf(lmax, __shfl_down(lmax, off));
    }
    int wave = threadIdx.x >> 6, lane = threadIdx.x & 63;
    if (lane == 0) { hf[wave] = lmin; hf[8 + wave] = lmax; }
    __syncthreads();
    float minv = fminf(fminf(hf[0], hf[1]), fminf(hf[2], hf[3]));
    float maxv = fmaxf(fmaxf(hf[8], hf[9]), fmaxf(hf[10], hf[11]));
    float invd = __fdiv_rn(256.0f, __fsub_rn(maxv, minv));
    __syncthreads();
    for (int i = threadIdx.x; i < NBINS * NCOPY; i += TPB) h[i] = 0;
    __syncthreads();

    int c = threadIdx.x & (NCOPY - 1);
    int n4 = n >> 2;
    int chunk = (n4 + GRID - 1) / GRID;
    int start = blockIdx.x * chunk;
    int end = start + chunk; if (end > n4) end = n4;
    const float4* in4 = (const float4*)in;
    int i = start + threadIdx.x;
    for (; i + 3 * TPB < end; i += 4 * TPB) {  // MLP=4, sequential lines
        float4 q0 = in4[i];
        float4 q1 = in4[i + TPB];
        float4 q2 = in4[i + 2 * TPB];
        float4 q3 = in4[i + 3 * TPB];
        hist4(q0, minv, invd, h, c);
        hist4(q1, minv, invd, h, c);
        hist4(q2, minv, invd, h, c);
        hist4(q3, minv, invd, h, c);
    }
    for (; i < end; i += TPB) {
        hist4(in4[i], minv, invd, h, c);
    }
    for (int j = (n4 << 2) + blockIdx.x * TPB + threadIdx.x; j < n; j += GRID * TPB) {
        atomicAdd(&h[bin_of(in[j], minv, invd) * NCOPY + c], 1u);
    }
    __syncthreads();
    for (int b = threadIdx.x; b < NBINS; b += TPB) {
        uint32_t s = 0;
#pragma unroll
        for (int k = 0; k < NCOPY; ++k) s += h[b * NCOPY + k];
        if (s) atomicAdd(&ws[HOFF + b], s);
    }
}

// Binarize with Otsu folded in: every block redundantly reduces min/max and
// computes the threshold (identical f32 math -> identical bit-exact result),
// then streams its contiguous chunk.
__global__ void __launch_bounds__(TPB) k_bin(const float* __restrict__ in,
                                             float* __restrict__ out,
                                             int n, const uint32_t* __restrict__ ws) {
    __shared__ float cnt[NBINS], ctr[NBINS], w1[NBINS], w2[NBINS],
                     cs[NBINS], csr[NBINS], scan[NBINS], tsh[1];
    const float* fws = (const float*)ws;
    {
        int i = threadIdx.x;
        // min/max reduction from per-block slots (scan[] as scratch)
        float lmin = INFINITY, lmax = -INFINITY;
        for (int k = i; k < GRID; k += TPB) {
            lmin = fminf(lmin, fws[MOFF + k]);
            lmax = fmaxf(lmax, fws[XOFF + k]);
        }
#pragma unroll
        for (int off = 32; off > 0; off >>= 1) {
            lmin = fminf(lmin, __shfl_down(lmin, off));
            lmax = fmaxf(lmax, __shfl_down(lmax, off));
        }
        int wave = i >> 6, lane = i & 63;
        if (lane == 0) { scan[wave] = lmin; scan[8 + wave] = lmax; }
        __syncthreads();
        float minv = fminf(fminf(scan[0], scan[1]), fminf(scan[2], scan[3]));
        float maxv = fmaxf(fmaxf(scan[8], scan[9]), fmaxf(scan[10], scan[11]));
        float delta = __fdiv_rn(__fsub_rn(maxv, minv), 256.0f);
        __syncthreads();

        cnt[i] = (float)ws[HOFF + i];
        float e0 = edge_at(i, minv, delta);
        float e1 = edge_at(i + 1, minv, delta);
        ctr[i] = __fmul_rn(0.5f, __fadd_rn(e0, e1));
        __syncthreads();

        // inclusive prefix scan of cnt -> w1
        scan[i] = cnt[i]; __syncthreads();
        for (int off = 1; off < NBINS; off <<= 1) {
            float v = scan[i];
            if (i >= off) v = __fadd_rn(scan[i - off], v);
            __syncthreads(); scan[i] = v; __syncthreads();
        }
        w1[i] = scan[i]; __syncthreads();

        // inclusive prefix scan of cnt*ctr -> cs
        scan[i] = __fmul_rn(cnt[i], ctr[i]); __syncthreads();
        for (int off = 1; off < NBINS; off <<= 1) {
            float v = scan[i];
            if (i >= off) v = __fadd_rn(scan[i - off], v);
            __syncthreads(); scan[i] = v; __syncthreads();
        }
        cs[i] = scan[i]; __syncthreads();

        // inclusive suffix scan of cnt -> w2
        scan[i] = cnt[i]; __syncthreads();
        for (int off = 1; off < NBINS; off <<= 1) {
            float v = scan[i];
            if (i + off < NBINS) v = __fadd_rn(v, scan[i + off]);
            __syncthreads(); scan[i] = v; __syncthreads();
        }
        w2[i] = scan[i]; __syncthreads();

        // inclusive suffix scan of cnt*ctr -> csr
        scan[i] = __fmul_rn(cnt[i], ctr[i]); __syncthreads();
        for (int off = 1; off < NBINS; off <<= 1) {
            float v = scan[i];
            if (i + off < NBINS) v = __fadd_rn(v, scan[i + off]);
            __syncthreads(); scan[i] = v; __syncthreads();
        }
        csr[i] = scan[i]; __syncthreads();

        // var12[i] = (w1[i]*w2[i+1]) * (m1[i]-m2[i+1])^2, i in [0, 254]
        if (i < NBINS - 1) {
            float m1 = __fdiv_rn(cs[i], fmaxf(w1[i], 1.0f));
            float m2 = __fdiv_rn(csr[i + 1], fmaxf(w2[i + 1], 1.0f));
            float d = __fsub_rn(m1, m2);
            float sq = __fmul_rn(d, d);
            scan[i] = __fmul_rn(__fmul_rn(w1[i], w2[i + 1]), sq);
        }
        __syncthreads();
        if (i == 0) {
            int best = 0; float bv = scan[0];
            for (int k = 1; k < NBINS - 1; ++k) {
                float v = scan[k];
                if (v > bv) { bv = v; best = k; }  // first-max like jnp.argmax
            }
            tsh[0] = ctr[best];
        }
        __syncthreads();
    }
    float t = tsh[0];

    int n4 = n >> 2;
    int chunk = (n4 + GRID - 1) / GRID;
    int start = blockIdx.x * chunk;
    int end = start + chunk; if (end > n4) end = n4;
    const float4* in4 = (const float4*)in;
    float4* out4 = (float4*)out;
    int i = start + threadIdx.x;
    for (; i + 3 * TPB < end; i += 4 * TPB) {  // MLP=4, sequential lines
        float4 v0 = in4[i];
        float4 v1 = in4[i + TPB];
        float4 v2 = in4[i + 2 * TPB];
        float4 v3 = in4[i + 3 * TPB];
        float4 r0, r1, r2, r3;
        r0.x = v0.x > t ? 1.0f : 0.0f; r0.y = v0.y > t ? 1.0f : 0.0f;
        r0.z = v0.z > t ? 1.0f : 0.0f; r0.w = v0.w > t ? 1.0f : 0.0f;
        r1.x = v1.x > t ? 1.0f : 0.0f; r1.y = v1.y > t ? 1.0f : 0.0f;
        r1.z = v1.z > t ? 1.0f : 0.0f; r1.w = v1.w > t ? 1.0f : 0.0f;
        r2.x = v2.x > t ? 1.0f : 0.0f; r2.y = v2.y > t ? 1.0f : 0.0f;
        r2.z = v2.z > t ? 1.0f : 0.0f; r2.w = v2.w > t ? 1.0f : 0.0f;
        r3.x = v3.x > t ? 1.0f : 0.0f; r3.y = v3.y > t ? 1.0f : 0.0f;
        r3.z = v3.z > t ? 1.0f : 0.0f; r3.w = v3.w > t ? 1.0f : 0.0f;
        out4[i] = r0;
        out4[i + TPB] = r1;
        out4[i + 2 * TPB] = r2;
        out4[i + 3 * TPB] = r3;
    }
    for (; i < end; i += TPB) {
        float4 v = in4[i];
        float4 r;
        r.x = v.x > t ? 1.0f : 0.0f;
        r.y = v.y > t ? 1.0f : 0.0f;
        r.z = v.z > t ? 1.0f : 0.0f;
        r.w = v.w > t ? 1.0f : 0.0f;
        out4[i] = r;
    }
    for (int j = (n4 << 2) + blockIdx.x * TPB + threadIdx.x; j < n; j += GRID * TPB) {
        out[j] = in[j] > t ? 1.0f : 0.0f;
    }
}

extern "C" void kernel_launch(void* const* d_in, const int* in_sizes, int n_in,
                              void* d_out, int out_size, void* d_ws, size_t ws_size,
                              hipStream_t stream) {
    const float* in = (const float*)d_in[0];
    float* out = (float*)d_out;
    uint32_t* ws = (uint32_t*)d_ws;
    int n = in_sizes[0];

    hipLaunchKernelGGL(k_minmax, dim3(GRID), dim3(TPB), 0, stream, in, n, ws);
    hipLaunchKernelGGL(k_hist, dim3(GRID), dim3(TPB), 0, stream, in, n, ws);
    hipLaunchKernelGGL(k_bin, dim3(GRID), dim3(TPB), 0, stream, in, out, n, ws);
}

// Round 14
// 144.023 us; speedup vs baseline: 1.5096x; 1.0391x over previous
//
#include <hip/hip_runtime.h>
#include <stdint.h>

#define NBINS 256
#define NCOPY 32      // one sub-histogram per LDS bank; 32 KiB LDS
#define GRID 2048
#define TPB 256
// ws word layout:
#define HOFF 4              // hist bins [4..260)
#define MOFF 512            // per-block mins [512..512+GRID)
#define XOFF (512 + GRID)   // per-block maxs
#define PKOFF 8192          // packed uchar4-bins array start (word index)

// Exact replication of jnp.histogram edge: edges[i] = f32(f32(i*delta) + min)
__device__ __forceinline__ float edge_at(int i, float minv, float delta) {
    return __fadd_rn(__fmul_rn((float)i, delta), minv);
}
__device__ __forceinline__ float min4(float4 v) {
    return fminf(fminf(v.x, v.y), fminf(v.z, v.w));
}
__device__ __forceinline__ float max4(float4 v) {
    return fmaxf(fmaxf(v.x, v.y), fmaxf(v.z, v.w));
}

__global__ void __launch_bounds__(TPB) k_minmax(const float* __restrict__ in,
                                                int n, uint32_t* ws) {
    float* fws = (float*)ws;
    int n4 = n >> 2;
    int chunk = (n4 + GRID - 1) / GRID;
    int start = blockIdx.x * chunk;
    int end = start + chunk; if (end > n4) end = n4;
    const float4* in4 = (const float4*)in;
    float vmin = INFINITY, vmax = -INFINITY;

    int i = start + threadIdx.x;
    for (; i + 7 * TPB < end; i += 8 * TPB) {  // MLP=8, sequential lines
        float4 v0 = in4[i];
        float4 v1 = in4[i + TPB];
        float4 v2 = in4[i + 2 * TPB];
        float4 v3 = in4[i + 3 * TPB];
        float4 v4 = in4[i + 4 * TPB];
        float4 v5 = in4[i + 5 * TPB];
        float4 v6 = in4[i + 6 * TPB];
        float4 v7 = in4[i + 7 * TPB];
        float mn0 = fminf(fminf(min4(v0), min4(v1)), fminf(min4(v2), min4(v3)));
        float mn1 = fminf(fminf(min4(v4), min4(v5)), fminf(min4(v6), min4(v7)));
        float mx0 = fmaxf(fmaxf(max4(v0), max4(v1)), fmaxf(max4(v2), max4(v3)));
        float mx1 = fmaxf(fmaxf(max4(v4), max4(v5)), fmaxf(max4(v6), max4(v7)));
        vmin = fminf(vmin, fminf(mn0, mn1));
        vmax = fmaxf(vmax, fmaxf(mx0, mx1));
    }
    for (; i < end; i += TPB) {
        float4 v = in4[i];
        vmin = fminf(vmin, min4(v));
        vmax = fmaxf(vmax, max4(v));
    }
    for (int j = (n4 << 2) + blockIdx.x * TPB + threadIdx.x; j < n; j += GRID * TPB) {
        float v = in[j];
        vmin = fminf(vmin, v);
        vmax = fmaxf(vmax, v);
    }
#pragma unroll
    for (int off = 32; off > 0; off >>= 1) {
        vmin = fminf(vmin, __shfl_down(vmin, off));
        vmax = fmaxf(vmax, __shfl_down(vmax, off));
    }
    __shared__ float smin[4], smax[4];
    int wave = threadIdx.x >> 6, lane = threadIdx.x & 63;
    if (lane == 0) { smin[wave] = vmin; smax[wave] = vmax; }
    __syncthreads();
    if (threadIdx.x == 0) {
        fws[MOFF + blockIdx.x] = fminf(fminf(smin[0], smin[1]), fminf(smin[2], smin[3]));
        fws[XOFF + blockIdx.x] = fmaxf(fmaxf(smax[0], smax[1]), fmaxf(smax[2], smax[3]));
    }
    if (blockIdx.x == 0) ws[HOFF + threadIdx.x] = 0;  // zero bins for k_hist
}

// bin = clamp((v-min)*256/(max-min), 0, 255). ±1ulp edge misbinning shifts a
// handful of counts -> var12 argmax unaffected; final output stays EXACT (see
// k_bin_packed: per-element verdicts are correct for all misbinning cases).
__device__ __forceinline__ int bin_of(float v, float minv, float invd) {
    float t = (v - minv) * invd;
    t = fminf(fmaxf(t, 0.0f), 255.0f);
    return (int)t;
}

// bin index + (v > center_of_bin) bit, center with the SAME _rn formula Otsu uses.
__device__ __forceinline__ uint32_t binbit(float v, float minv, float invd,
                                           float delta, uint32_t* bit) {
    int j = bin_of(v, minv, invd);
    float e0 = edge_at(j, minv, delta);
    float e1 = edge_at(j + 1, minv, delta);
    float ctr = __fmul_rn(0.5f, __fadd_rn(e0, e1));
    *bit = (v > ctr) ? 1u : 0u;
    return (uint32_t)j;
}

// Histogram; when packed!=0 also emits per-quad uchar4 bins + 4 "v>center" bits.
__global__ void __launch_bounds__(TPB) k_hist(const float* __restrict__ in,
                                              int n, uint32_t* ws, int packed) {
    __shared__ uint32_t h[NBINS * NCOPY];  // 32 KiB
    float* hf = (float*)h;
    float* fws = (float*)ws;

    // prologue: reduce per-block min/max slots
    float lmin = INFINITY, lmax = -INFINITY;
    for (int k = threadIdx.x; k < GRID; k += TPB) {
        lmin = fminf(lmin, fws[MOFF + k]);
        lmax = fmaxf(lmax, fws[XOFF + k]);
    }
#pragma unroll
    for (int off = 32; off > 0; off >>= 1) {
        lmin = fminf(lmin, __shfl_down(lmin, off));
        lmax = fmaxf(lmax, __shfl_down(lmax, off));
    }
    int wave = threadIdx.x >> 6, lane = threadIdx.x & 63;
    if (lane == 0) { hf[wave] = lmin; hf[8 + wave] = lmax; }
    __syncthreads();
    float minv = fminf(fminf(hf[0], hf[1]), fminf(hf[2], hf[3]));
    float maxv = fmaxf(fmaxf(hf[8], hf[9]), fmaxf(hf[10], hf[11]));
    float invd = __fdiv_rn(256.0f, __fsub_rn(maxv, minv));
    float delta = __fdiv_rn(__fsub_rn(maxv, minv), 256.0f);
    __syncthreads();
    for (int i = threadIdx.x; i < NBINS * NCOPY; i += TPB) h[i] = 0;
    __syncthreads();

    int c = threadIdx.x & (NCOPY - 1);
    int n4 = n >> 2;
    int chunk = (n4 + GRID - 1) / GRID;
    int start = blockIdx.x * chunk;
    int end = start + chunk; if (end > n4) end = n4;
    const float4* in4 = (const float4*)in;
    uint32_t* bins = ws + PKOFF;
    uint8_t* bits8 = (uint8_t*)(ws + PKOFF + n4);

    for (int i = start + threadIdx.x; i < end; i += TPB) {
        float4 q = in4[i];
        uint32_t b0, b1, b2, b3;
        uint32_t j0 = binbit(q.x, minv, invd, delta, &b0);
        uint32_t j1 = binbit(q.y, minv, invd, delta, &b1);
        uint32_t j2 = binbit(q.z, minv, invd, delta, &b2);
        uint32_t j3 = binbit(q.w, minv, invd, delta, &b3);
        atomicAdd(&h[j0 * NCOPY + c], 1u);
        atomicAdd(&h[j1 * NCOPY + c], 1u);
        atomicAdd(&h[j2 * NCOPY + c], 1u);
        atomicAdd(&h[j3 * NCOPY + c], 1u);
        if (packed) {
            bins[i] = j0 | (j1 << 8) | (j2 << 16) | (j3 << 24);
            bits8[i] = (uint8_t)(b0 | (b1 << 1) | (b2 << 2) | (b3 << 3));
        }
    }
    for (int j = (n4 << 2) + blockIdx.x * TPB + threadIdx.x; j < n; j += GRID * TPB) {
        atomicAdd(&h[bin_of(in[j], minv, invd) * NCOPY + c], 1u);
    }
    __syncthreads();
    for (int b = threadIdx.x; b < NBINS; b += TPB) {
        uint32_t s = 0;
#pragma unroll
        for (int k = 0; k < NCOPY; ++k) s += h[b * NCOPY + k];
        if (s) atomicAdd(&ws[HOFF + b], s);
    }
}

// Shared Otsu prologue: returns best bin (and thresh for the scalar tail).
__device__ __forceinline__ void otsu_prologue(const uint32_t* __restrict__ ws,
                                              int* best_out, float* thresh_out) {
    __shared__ float cnt[NBINS], ctr[NBINS], w1[NBINS], w2[NBINS],
                     cs[NBINS], csr[NBINS], scan[NBINS];
    __shared__ int sbest;
    const float* fws = (const float*)ws;
    int i = threadIdx.x;

    float lmin = INFINITY, lmax = -INFINITY;
    for (int k = i; k < GRID; k += TPB) {
        lmin = fminf(lmin, fws[MOFF + k]);
        lmax = fmaxf(lmax, fws[XOFF + k]);
    }
#pragma unroll
    for (int off = 32; off > 0; off >>= 1) {
        lmin = fminf(lmin, __shfl_down(lmin, off));
        lmax = fmaxf(lmax, __shfl_down(lmax, off));
    }
    int wave = i >> 6, lane = i & 63;
    if (lane == 0) { scan[wave] = lmin; scan[8 + wave] = lmax; }
    __syncthreads();
    float minv = fminf(fminf(scan[0], scan[1]), fminf(scan[2], scan[3]));
    float maxv = fmaxf(fmaxf(scan[8], scan[9]), fmaxf(scan[10], scan[11]));
    float delta = __fdiv_rn(__fsub_rn(maxv, minv), 256.0f);
    __syncthreads();

    cnt[i] = (float)ws[HOFF + i];
    float e0 = edge_at(i, minv, delta);
    float e1 = edge_at(i + 1, minv, delta);
    ctr[i] = __fmul_rn(0.5f, __fadd_rn(e0, e1));
    __syncthreads();

    scan[i] = cnt[i]; __syncthreads();
    for (int off = 1; off < NBINS; off <<= 1) {
        float v = scan[i];
        if (i >= off) v = __fadd_rn(scan[i - off], v);
        __syncthreads(); scan[i] = v; __syncthreads();
    }
    w1[i] = scan[i]; __syncthreads();

    scan[i] = __fmul_rn(cnt[i], ctr[i]); __syncthreads();
    for (int off = 1; off < NBINS; off <<= 1) {
        float v = scan[i];
        if (i >= off) v = __fadd_rn(scan[i - off], v);
        __syncthreads(); scan[i] = v; __syncthreads();
    }
    cs[i] = scan[i]; __syncthreads();

    scan[i] = cnt[i]; __syncthreads();
    for (int off = 1; off < NBINS; off <<= 1) {
        float v = scan[i];
        if (i + off < NBINS) v = __fadd_rn(v, scan[i + off]);
        __syncthreads(); scan[i] = v; __syncthreads();
    }
    w2[i] = scan[i]; __syncthreads();

    scan[i] = __fmul_rn(cnt[i], ctr[i]); __syncthreads();
    for (int off = 1; off < NBINS; off <<= 1) {
        float v = scan[i];
        if (i + off < NBINS) v = __fadd_rn(v, scan[i + off]);
        __syncthreads(); scan[i] = v; __syncthreads();
    }
    csr[i] = scan[i]; __syncthreads();

    if (i < NBINS - 1) {
        float m1 = __fdiv_rn(cs[i], fmaxf(w1[i], 1.0f));
        float m2 = __fdiv_rn(csr[i + 1], fmaxf(w2[i + 1], 1.0f));
        float d = __fsub_rn(m1, m2);
        scan[i] = __fmul_rn(__fmul_rn(w1[i], w2[i + 1]), __fmul_rn(d, d));
    }
    __syncthreads();
    if (i == 0) {
        int best = 0; float bv = scan[0];
        for (int k = 1; k < NBINS - 1; ++k) {
            float v = scan[k];
            if (v > bv) { bv = v; best = k; }  // first-max like jnp.argmax
        }
        sbest = best;
        scan[0] = ctr[best];
    }
    __syncthreads();
    *best_out = sbest;
    *thresh_out = scan[0];
    __syncthreads();
}

// Packed path: read bins+bits (42MB, L3-hot) instead of 134MB f32.
__global__ void __launch_bounds__(TPB) k_bin_packed(const float* __restrict__ in,
                                                    float* __restrict__ out,
                                                    int n,
                                                    const uint32_t* __restrict__ ws) {
    int best; float t;
    otsu_prologue(ws, &best, &t);

    int n4 = n >> 2;
    int chunk = (n4 + GRID - 1) / GRID;
    int start = blockIdx.x * chunk;
    int end = start + chunk; if (end > n4) end = n4;
    const uint32_t* bins = ws + PKOFF;
    const uint8_t* bits8 = (const uint8_t*)(ws + PKOFF + n4);
    float4* out4 = (float4*)out;
    uint32_t ubest = (uint32_t)best;

    for (int i = start + threadIdx.x; i < end; i += TPB) {
        uint32_t u = bins[i];
        uint32_t bt = bits8[i];
        float4 r;
        uint32_t j0 = u & 255u, j1 = (u >> 8) & 255u,
                 j2 = (u >> 16) & 255u, j3 = (u >> 24) & 255u;
        r.x = (j0 > ubest || (j0 == ubest && (bt & 1u))) ? 1.0f : 0.0f;
        r.y = (j1 > ubest || (j1 == ubest && (bt & 2u))) ? 1.0f : 0.0f;
        r.z = (j2 > ubest || (j2 == ubest && (bt & 4u))) ? 1.0f : 0.0f;
        r.w = (j3 > ubest || (j3 == ubest && (bt & 8u))) ? 1.0f : 0.0f;
        out4[i] = r;
    }
    for (int j = (n4 << 2) + blockIdx.x * TPB + threadIdx.x; j < n; j += GRID * TPB) {
        out[j] = in[j] > t ? 1.0f : 0.0f;
    }
}

// Fallback (ws too small): direct re-read of f32 input (R13 path).
__global__ void __launch_bounds__(TPB) k_bin_direct(const float* __restrict__ in,
                                                    float* __restrict__ out,
                                                    int n,
                                                    const uint32_t* __restrict__ ws) {
    int best; float t;
    otsu_prologue(ws, &best, &t);

    int n4 = n >> 2;
    int chunk = (n4 + GRID - 1) / GRID;
    int start = blockIdx.x * chunk;
    int end = start + chunk; if (end > n4) end = n4;
    const float4* in4 = (const float4*)in;
    float4* out4 = (float4*)out;
    int i = start + threadIdx.x;
    for (; i + 3 * TPB < end; i += 4 * TPB) {
        float4 v0 = in4[i];
        float4 v1 = in4[i + TPB];
        float4 v2 = in4[i + 2 * TPB];
        float4 v3 = in4[i + 3 * TPB];
        float4 r0, r1, r2, r3;
        r0.x = v0.x > t ? 1.0f : 0.0f; r0.y = v0.y > t ? 1.0f : 0.0f;
        r0.z = v0.z > t ? 1.0f : 0.0f; r0.w = v0.w > t ? 1.0f : 0.0f;
        r1.x = v1.x > t ? 1.0f : 0.0f; r1.y = v1.y > t ? 1.0f : 0.0f;
        r1.z = v1.z > t ? 1.0f : 0.0f; r1.w = v1.w > t ? 1.0f : 0.0f;
        r2.x = v2.x > t ? 1.0f : 0.0f; r2.y = v2.y > t ? 1.0f : 0.0f;
        r2.z = v2.z > t ? 1.0f : 0.0f; r2.w = v2.w > t ? 1.0f : 0.0f;
        r3.x = v3.x > t ? 1.0f : 0.0f; r3.y = v3.y > t ? 1.0f : 0.0f;
        r3.z = v3.z > t ? 1.0f : 0.0f; r3.w = v3.w > t ? 1.0f : 0.0f;
        out4[i] = r0;
        out4[i + TPB] = r1;
        out4[i + 2 * TPB] = r2;
        out4[i + 3 * TPB] = r3;
    }
    for (; i < end; i += TPB) {
        float4 v = in4[i];
        float4 r;
        r.x = v.x > t ? 1.0f : 0.0f;
        r.y = v.y > t ? 1.0f : 0.0f;
        r.z = v.z > t ? 1.0f : 0.0f;
        r.w = v.w > t ? 1.0f : 0.0f;
        out4[i] = r;
    }
    for (int j = (n4 << 2) + blockIdx.x * TPB + threadIdx.x; j < n; j += GRID * TPB) {
        out[j] = in[j] > t ? 1.0f : 0.0f;
    }
}

extern "C" void kernel_launch(void* const* d_in, const int* in_sizes, int n_in,
                              void* d_out, int out_size, void* d_ws, size_t ws_size,
                              hipStream_t stream) {
    const float* in = (const float*)d_in[0];
    float* out = (float*)d_out;
    uint32_t* ws = (uint32_t*)d_ws;
    int n = in_sizes[0];
    int n4 = n >> 2;

    size_t need = (size_t)(PKOFF + (size_t)n4) * 4 + (size_t)n4;  // bins + bits
    int packed = (ws_size >= need) ? 1 : 0;

    hipLaunchKernelGGL(k_minmax, dim3(GRID), dim3(TPB), 0, stream, in, n, ws);
    hipLaunchKernelGGL(k_hist, dim3(GRID), dim3(TPB), 0, stream, in, n, ws, packed);
    if (packed) {
        hipLaunchKernelGGL(k_bin_packed, dim3(GRID), dim3(TPB), 0, stream,
                           in, out, n, ws);
    } else {
        hipLaunchKernelGGL(k_bin_direct, dim3(GRID), dim3(TPB), 0, stream,
                           in, out, n, ws);
    }
}